// Round 4
// baseline (656.778 us; speedup 1.0000x reference)
//
#include <hip/hip_runtime.h>
#include <hip/hip_bf16.h>
#include <math.h>

#define B_    4
#define CIN   128
#define NPTS  2048
#define DIM   256
#define PH    64
#define HIDN  1024
#define KNN_  16
#define BN    (B_*NPTS)      /* 8192  */
#define CC    (BN*KNN_)      /* 131072 */
#define EPS_  1e-5f

typedef __bf16 bf16;
typedef __bf16 bf16x8 __attribute__((ext_vector_type(8)));
typedef __bf16 bf16x4 __attribute__((ext_vector_type(4)));
typedef float  f32x4  __attribute__((ext_vector_type(4)));

// ---------------------------------------------------------------------------
// prep: weight converts/transposes + bn folding + fused bias vectors
// Decomposition (all pre-relu ops are linear):
//   aw1.(q_i - k_j + pe_c) = Waq.h_i - Wak.h_j + M.hid_c + bq - (Wak part of bk)
//   Waq = aw1.qw, Wak = aw1.kw, M = aw1.pw2
//   bq[j] = aw1.(qb + pb2),  bk[j] = aw1.kb
// ---------------------------------------------------------------------------
__global__ __launch_bounds__(256) void prep_kernel(
    const float* __restrict__ ls_w, const float* __restrict__ qw,
    const float* __restrict__ kw,   const float* __restrict__ vw,
    const float* __restrict__ pw2,  const float* __restrict__ aw1,
    const float* __restrict__ aw2,  const float* __restrict__ lw,
    const float* __restrict__ qb,   const float* __restrict__ kb,
    const float* __restrict__ pb2,
    const float* __restrict__ pb1,  const float* __restrict__ pg,
    const float* __restrict__ pbeta,const float* __restrict__ pmean,
    const float* __restrict__ pvar,
    const float* __restrict__ ab1,  const float* __restrict__ ag,
    const float* __restrict__ abeta,const float* __restrict__ amean,
    const float* __restrict__ avar,
    bf16* ls_wb, bf16* vwb, bf16* qwt, bf16* kwt,
    bf16* pw2b, bf16* pw2t, bf16* aw1b, bf16* aw2b, bf16* lwb,
    float* pe_scale, float* pe_shift, float* at_scale, float* at_shift,
    float* bq, float* bk, float* zeros)
{
  long e = (long)blockIdx.x * 256 + threadIdx.x;
  if (e < 32768)  { ls_wb[e] = (bf16)ls_w[e]; return; } e -= 32768;
  if (e < 65536)  { vwb[e]   = (bf16)vw[e];   return; } e -= 65536;
  if (e < 65536)  { int c = (int)(e >> 8), o = (int)(e & 255);
                    qwt[e] = (bf16)qw[o * 256 + c]; return; } e -= 65536;
  if (e < 65536)  { int c = (int)(e >> 8), o = (int)(e & 255);
                    kwt[e] = (bf16)kw[o * 256 + c]; return; } e -= 65536;
  if (e < 16384)  { pw2b[e] = (bf16)pw2[e];   return; } e -= 16384;
  if (e < 16384)  { int ph = (int)(e >> 8), o = (int)(e & 255);
                    pw2t[e] = (bf16)pw2[o * 64 + ph]; return; } e -= 16384;
  if (e < 262144) { aw1b[e] = (bf16)aw1[e];   return; } e -= 262144;
  if (e < 262144) { aw2b[e] = (bf16)aw2[e];   return; } e -= 262144;
  if (e < 32768)  { lwb[e]  = (bf16)lw[e];    return; } e -= 32768;
  if (e < 64) {
    float sc = pg[e] * rsqrtf(pvar[e] + EPS_);
    pe_scale[e] = sc;
    pe_shift[e] = sc * pb1[e] + pbeta[e] - pmean[e] * sc;
    return;
  } e -= 64;
  if (e < 1024) {
    float sc = ag[e] * rsqrtf(avar[e] + EPS_);
    at_scale[e] = sc;
    at_shift[e] = sc * ab1[e] + abeta[e] - amean[e] * sc;
    return;
  } e -= 1024;
  if (e < 1024) {
    float s = 0.f;
    for (int o = 0; o < 256; ++o) s += aw1[e * 256 + o] * (qb[o] + pb2[o]);
    bq[e] = s; return;
  } e -= 1024;
  if (e < 1024) {
    float s = 0.f;
    for (int o = 0; o < 256; ++o) s += aw1[e * 256 + o] * kb[o];
    bk[e] = s; return;
  } e -= 1024;
  if (e < 1024) { zeros[e] = 0.f; }
}

// ---------------------------------------------------------------------------
// transpose x (B,CIN,N) fp32 -> xT (BN, CIN) bf16  (channel-last)
// ---------------------------------------------------------------------------
__global__ __launch_bounds__(256) void transpose_x_kernel(
    const float* __restrict__ x, bf16* __restrict__ xT)
{
  long e = (long)blockIdx.x * 256 + threadIdx.x;
  int ch = (int)(e & (CIN - 1));
  long i = e >> 7;
  int n = (int)(i & (NPTS - 1));
  int b = (int)(i >> 11);
  xT[e] = (bf16)x[((long)b * CIN + ch) * NPTS + n];
}

// ---------------------------------------------------------------------------
// KNN: one WAVE per query point; dists in 32 regs/lane; shfl argmin x16
// ---------------------------------------------------------------------------
__global__ __launch_bounds__(256) void knn_kernel(
    const float* __restrict__ pos, int* __restrict__ idx_out)
{
  __shared__ float px[NPTS], py[NPTS], pz[NPTS];
  const int tid = threadIdx.x;
  const int lane = tid & 63, wave = tid >> 6;
  const int q = blockIdx.x * 4 + wave;
  const int b = q >> 11;
  const int n = q & (NPTS - 1);
  const float* p = pos + (long)b * 3 * NPTS;
  for (int j = tid; j < NPTS; j += 256) {
    px[j] = p[j]; py[j] = p[NPTS + j]; pz[j] = p[2 * NPTS + j];
  }
  __syncthreads();
  float qx = px[n], qy = py[n], qz = pz[n];
  float qs = qx * qx + qy * qy + qz * qz;
  float d[32];
#pragma unroll
  for (int j = 0; j < 32; ++j) {
    int pt = j * 64 + lane;
    float x = px[pt], y = py[pt], z = pz[pt];
    float s2 = x * x + y * y + z * z;
    float dt = qx * x + qy * y + qz * z;
    d[j] = qs + s2 - 2.f * dt;
  }
  for (int r = 0; r < KNN_; ++r) {
    float bv = 1e30f; int bj = 0;
#pragma unroll
    for (int j = 0; j < 32; ++j)
      if (d[j] < bv) { bv = d[j]; bj = j; }
    int bi = bj * 64 + lane;
#pragma unroll
    for (int off = 32; off >= 1; off >>= 1) {
      float ov = __shfl_xor(bv, off);
      int   oi = __shfl_xor(bi, off);
      if (ov < bv || (ov == bv && oi < bi)) { bv = ov; bi = oi; }
    }
    if (lane == 0) idx_out[(long)q * KNN_ + r] = bi;
#pragma unroll
    for (int j = 0; j < 32; ++j)
      if (bi == j * 64 + lane) d[j] = 1e30f;
  }
}

// ---------------------------------------------------------------------------
// generic channel-last GEMM: out[i][o] = sum_k inT[i][k]*W[o][k] + bias[o]
// ---------------------------------------------------------------------------
template<int KD, bool OBF16>
__global__ __launch_bounds__(256) void gemmT_kernel(
    const bf16* __restrict__ inT, const bf16* __restrict__ Wb,
    const float* __restrict__ bias, void* __restrict__ outp, int O)
{
  const int tid = threadIdx.x;
  const int lane = tid & 63, wave = tid >> 6;
  const int row16 = lane & 15, grp = lane >> 4;
  const long i0 = (long)blockIdx.x * 64 + (wave & 1) * 32;
  const long o0 = (long)blockIdx.y * 64 + (wave >> 1) * 32;
  f32x4 acc[2][2] = {};
  const bf16* a0p = inT + (i0 + row16) * KD + grp * 8;
  const bf16* a1p = a0p + 16 * KD;
  const bf16* b0p = Wb + (o0 + row16) * KD + grp * 8;
  const bf16* b1p = b0p + 16 * KD;
#pragma unroll
  for (int ks = 0; ks < KD / 32; ++ks) {
    bf16x8 a0 = *(const bf16x8*)(a0p + ks * 32);
    bf16x8 a1 = *(const bf16x8*)(a1p + ks * 32);
    bf16x8 b0 = *(const bf16x8*)(b0p + ks * 32);
    bf16x8 b1 = *(const bf16x8*)(b1p + ks * 32);
    acc[0][0] = __builtin_amdgcn_mfma_f32_16x16x32_bf16(a0, b0, acc[0][0], 0, 0, 0);
    acc[0][1] = __builtin_amdgcn_mfma_f32_16x16x32_bf16(a0, b1, acc[0][1], 0, 0, 0);
    acc[1][0] = __builtin_amdgcn_mfma_f32_16x16x32_bf16(a1, b0, acc[1][0], 0, 0, 0);
    acc[1][1] = __builtin_amdgcn_mfma_f32_16x16x32_bf16(a1, b1, acc[1][1], 0, 0, 0);
  }
#pragma unroll
  for (int ot = 0; ot < 2; ++ot) {
    long o = o0 + ot * 16 + row16;
    float bv = bias[o];
#pragma unroll
    for (int it = 0; it < 2; ++it) {
#pragma unroll
      for (int r = 0; r < 4; ++r) {
        long i = i0 + it * 16 + grp * 4 + r;
        float v = acc[it][ot][r] + bv;
        if (OBF16) ((bf16*)outp)[i * O + o] = (bf16)v;
        else       ((float*)outp)[i * O + o] = v;
      }
    }
  }
}

// ---------------------------------------------------------------------------
// FUSED attention v3 (decomposed):
//   t_pre[c][j] = A1q[i][j] - A1k[nb][j] + (M.hid_c)[j]   (A1 in epilogue)
//   t = relu(at_scale*t_pre + at_shift);  attn = ab2 + aw2.t
//   softmax over K; agg = sum p*(v_gather + pe);  pe = pw2.hid + pb2
// No u tensor, no k-gather. LDS ~27.2KB -> 4-5 blocks/CU (VGPR-capped 4).
// ---------------------------------------------------------------------------
__global__ __launch_bounds__(256, 4) void attn_fused_kernel(
    const bf16* __restrict__ vTb, const float* __restrict__ pos,
    const int* __restrict__ idx, const float* __restrict__ pw1,
    const float* __restrict__ pe_scale, const float* __restrict__ pe_shift,
    const bf16* __restrict__ pw2b, const float* __restrict__ pb2,
    const bf16* __restrict__ Mwb, const bf16* __restrict__ A1q,
    const bf16* __restrict__ A1k, const bf16* __restrict__ aw2b,
    const float* __restrict__ at_scale, const float* __restrict__ at_shift,
    const float* __restrict__ ab2, bf16* __restrict__ aggT)
{
  __shared__ __align__(16) bf16 hid_lds[64][72];   //  9.2 KB
  __shared__ __align__(16) bf16 t_lds[64][136];    // 17.4 KB
  __shared__ float rel_lds[64][4];
  __shared__ int   idx_lds[64];

  const int tid = threadIdx.x;
  const int lane = tid & 63, wave = tid >> 6;
  const int row16 = lane & 15, grp = lane >> 4;
  const long c0 = (long)blockIdx.x * 64;
  const int bn0 = blockIdx.x * 4;
  const int b = bn0 >> 11;
  const float* pB = pos + (long)b * 3 * NPTS;
  const int os = wave * 64;             // GEMM2/pe output-channel slab
  const int hs = wave * 32;             // GEMM1 hidden slab (within 128)

  // ---- stage idx + pos_rel ----
  if (tid < 64) {
    int nb = idx[c0 + tid];
    idx_lds[tid] = nb;
    int n = (bn0 + (tid >> 4)) & (NPTS - 1);
    rel_lds[tid][0] = pB[n] - pB[nb];
    rel_lds[tid][1] = pB[NPTS + n] - pB[NPTS + nb];
    rel_lds[tid][2] = pB[2 * NPTS + n] - pB[2 * NPTS + nb];
  }
  __syncthreads();

  // ---- hid = relu(bn(pw1 . rel)) ----
  {
    int c = tid & 63, jq = tid >> 6;
    float rx = rel_lds[c][0], ry = rel_lds[c][1], rz = rel_lds[c][2];
#pragma unroll
    for (int jj = 0; jj < 16; ++jj) {
      int j = jq * 16 + jj;
      float v = pw1[j * 3] * rx + pw1[j * 3 + 1] * ry + pw1[j * 3 + 2] * rz;
      v = pe_scale[j] * v + pe_shift[j];
      hid_lds[c][j] = (bf16)fmaxf(v, 0.f);
    }
  }
  __syncthreads();

  // per-lane neighbor ids for the GEMM1 epilogue (col = row16)
  int nbv[4];
#pragma unroll
  for (int ct = 0; ct < 4; ++ct) nbv[ct] = idx_lds[ct * 16 + row16];

  // ---- pe GEMM: pe[c][o-slab] ----
  f32x4 accpe[4][4] = {};
#pragma unroll
  for (int ks = 0; ks < 2; ++ks) {
    bf16x8 ah[4];
#pragma unroll
    for (int ct = 0; ct < 4; ++ct)
      ah[ct] = *(const bf16x8*)&hid_lds[ct * 16 + row16][ks * 32 + grp * 8];
#pragma unroll
    for (int ot = 0; ot < 4; ++ot) {
      bf16x8 bw = *(const bf16x8*)(pw2b + (long)(os + ot * 16 + row16) * PH + ks * 32 + grp * 8);
#pragma unroll
      for (int ct = 0; ct < 4; ++ct)
        accpe[ct][ot] = __builtin_amdgcn_mfma_f32_16x16x32_bf16(ah[ct], bw, accpe[ct][ot], 0, 0, 0);
    }
  }
  bf16x4 pe_bf[4][4];
#pragma unroll
  for (int ot = 0; ot < 4; ++ot) {
    float pb2v = pb2[os + ot * 16 + row16];
#pragma unroll
    for (int ct = 0; ct < 4; ++ct)
#pragma unroll
      for (int r = 0; r < 4; ++r)
        pe_bf[ct][ot][r] = (bf16)(accpe[ct][ot][r] + pb2v);
  }

  // ---- MLP loop over 8 x 128-hid chunks ----
  f32x4 acc2[4][4] = {};
  for (int jc = 0; jc < 8; ++jc) {
    const int hg = jc * 128 + hs;
    // GEMM1: M.hid (K=64), D row=j col=c
    f32x4 acc1[4][2] = {};
#pragma unroll
    for (int ks = 0; ks < 2; ++ks) {
      bf16x8 mw[2], hf[4];
#pragma unroll
      for (int jt = 0; jt < 2; ++jt)
        mw[jt] = *(const bf16x8*)(Mwb + (long)(hg + jt * 16 + row16) * PH + ks * 32 + grp * 8);
#pragma unroll
      for (int ct = 0; ct < 4; ++ct)
        hf[ct] = *(const bf16x8*)&hid_lds[ct * 16 + row16][ks * 32 + grp * 8];
#pragma unroll
      for (int ct = 0; ct < 4; ++ct)
#pragma unroll
        for (int jt = 0; jt < 2; ++jt)
          acc1[ct][jt] = __builtin_amdgcn_mfma_f32_16x16x32_bf16(mw[jt], hf[ct], acc1[ct][jt], 0, 0, 0);
    }
    // epilogue: + A1q - A1k, bn+relu, b64 store to t
#pragma unroll
    for (int jt = 0; jt < 2; ++jt) {
      int jb = hg + jt * 16 + grp * 4;
      f32x4 sc4 = *(const f32x4*)&at_scale[jb];
      f32x4 sh4 = *(const f32x4*)&at_shift[jb];
#pragma unroll
      for (int ct = 0; ct < 4; ++ct) {
        bf16x4 aq = *(const bf16x4*)(A1q + (long)(bn0 + ct) * HIDN + jb);
        bf16x4 ak = *(const bf16x4*)(A1k + ((long)b * NPTS + nbv[ct]) * HIDN + jb);
        bf16x4 pk;
#pragma unroll
        for (int r = 0; r < 4; ++r) {
          float v = sc4[r] * (acc1[ct][jt][r] + (float)aq[r] - (float)ak[r]) + sh4[r];
          pk[r] = (bf16)fmaxf(v, 0.f);
        }
        *(bf16x4*)&t_lds[ct * 16 + row16][hs + jt * 16 + grp * 4] = pk;
      }
    }
    __syncthreads();
    // GEMM2: acc2 += t . aw2 (K=128 chunk)
#pragma unroll
    for (int ks2 = 0; ks2 < 4; ++ks2) {
      bf16x8 a2[4], b2;
#pragma unroll
      for (int ct = 0; ct < 4; ++ct)
        a2[ct] = *(const bf16x8*)&t_lds[ct * 16 + row16][ks2 * 32 + grp * 8];
#pragma unroll
      for (int ot = 0; ot < 4; ++ot) {
        b2 = *(const bf16x8*)(aw2b + (long)(os + ot * 16 + row16) * HIDN + jc * 128 + ks2 * 32 + grp * 8);
#pragma unroll
        for (int ct = 0; ct < 4; ++ct)
          acc2[ct][ot] = __builtin_amdgcn_mfma_f32_16x16x32_bf16(a2[ct], b2, acc2[ct][ot], 0, 0, 0);
      }
    }
    __syncthreads();
  }

  // ---- softmax over K + aggregation ----
#pragma unroll
  for (int ct = 0; ct < 4; ++ct) {
#pragma unroll
    for (int ot = 0; ot < 4; ++ot) {
      int o = os + ot * 16 + row16;
      float ab = ab2[o];
      float l[4];
      float m = -1e30f;
#pragma unroll
      for (int r = 0; r < 4; ++r) {
        l[r] = acc2[ct][ot][r] + ab;
        m = fmaxf(m, l[r]);
      }
      m = fmaxf(m, __shfl_xor(m, 16));
      m = fmaxf(m, __shfl_xor(m, 32));
      float s = 0.f;
#pragma unroll
      for (int r = 0; r < 4; ++r) { l[r] = expf(l[r] - m); s += l[r]; }
      s += __shfl_xor(s, 16);
      s += __shfl_xor(s, 32);
      float inv = 1.f / s;
      float agg = 0.f;
#pragma unroll
      for (int r = 0; r < 4; ++r) {
        int c = ct * 16 + grp * 4 + r;
        int nb = idx_lds[c];
        float vv = (float)vTb[((long)b * NPTS + nb) * DIM + o];
        agg += l[r] * (vv + (float)pe_bf[ct][ot][r]);
      }
      agg *= inv;
      agg += __shfl_xor(agg, 16);
      agg += __shfl_xor(agg, 32);
      if (grp == 0) aggT[(long)(bn0 + ct) * DIM + o] = (bf16)agg;
    }
  }
}

// ---------------------------------------------------------------------------
// final: out[b][o][n] = lw . agg + lb + identity
// ---------------------------------------------------------------------------
__global__ __launch_bounds__(256) void final_kernel(
    const bf16* __restrict__ aggT, const bf16* __restrict__ lwb,
    const float* __restrict__ lb, const float* __restrict__ x,
    float* __restrict__ out)
{
  const int tid = threadIdx.x;
  const int lane = tid & 63, wave = tid >> 6;
  const int row16 = lane & 15, grp = lane >> 4;
  const long i0 = (long)blockIdx.x * 64 + (wave & 1) * 32;
  const int o0 = blockIdx.y * 64 + (wave >> 1) * 32;
  f32x4 acc[2][2] = {};
  const bf16* a0p = aggT + (i0 + row16) * DIM + grp * 8;
  const bf16* a1p = a0p + 16 * DIM;
  const bf16* b0p = lwb + (long)(o0 + row16) * DIM + grp * 8;
  const bf16* b1p = b0p + 16 * DIM;
#pragma unroll
  for (int ks = 0; ks < 8; ++ks) {
    bf16x8 a0 = *(const bf16x8*)(a0p + ks * 32);
    bf16x8 a1 = *(const bf16x8*)(a1p + ks * 32);
    bf16x8 b0 = *(const bf16x8*)(b0p + ks * 32);
    bf16x8 b1 = *(const bf16x8*)(b1p + ks * 32);
    acc[0][0] = __builtin_amdgcn_mfma_f32_16x16x32_bf16(a0, b0, acc[0][0], 0, 0, 0);
    acc[0][1] = __builtin_amdgcn_mfma_f32_16x16x32_bf16(a0, b1, acc[0][1], 0, 0, 0);
    acc[1][0] = __builtin_amdgcn_mfma_f32_16x16x32_bf16(a1, b0, acc[1][0], 0, 0, 0);
    acc[1][1] = __builtin_amdgcn_mfma_f32_16x16x32_bf16(a1, b1, acc[1][1], 0, 0, 0);
  }
#pragma unroll
  for (int ot = 0; ot < 2; ++ot) {
    int o = o0 + ot * 16 + row16;
    float bv = lb[o];
#pragma unroll
    for (int it = 0; it < 2; ++it) {
#pragma unroll
      for (int r = 0; r < 4; ++r) {
        long i = i0 + it * 16 + grp * 4 + r;
        int bb = (int)(i >> 11);
        int n = (int)(i & (NPTS - 1));
        long off = ((long)bb * CIN + o) * NPTS + n;
        out[off] = acc[it][ot][r] + bv + x[off];
      }
    }
  }
}

// ---------------------------------------------------------------------------
extern "C" void kernel_launch(void* const* d_in, const int* in_sizes, int n_in,
                              void* d_out, int out_size, void* d_ws, size_t ws_size,
                              hipStream_t stream)
{
  const float* x     = (const float*)d_in[0];
  const float* pos   = (const float*)d_in[1];
  const float* ls_w  = (const float*)d_in[2];
  const float* ls_b  = (const float*)d_in[3];
  const float* kw    = (const float*)d_in[4];
  const float* kb    = (const float*)d_in[5];
  const float* qw    = (const float*)d_in[6];
  const float* qb    = (const float*)d_in[7];
  const float* vw    = (const float*)d_in[8];
  const float* vb    = (const float*)d_in[9];
  const float* pw1   = (const float*)d_in[10];
  const float* pb1   = (const float*)d_in[11];
  const float* pg    = (const float*)d_in[12];
  const float* pbeta = (const float*)d_in[13];
  const float* pmean = (const float*)d_in[14];
  const float* pvar  = (const float*)d_in[15];
  const float* pw2   = (const float*)d_in[16];
  const float* pb2   = (const float*)d_in[17];
  const float* aw1   = (const float*)d_in[18];
  const float* ab1   = (const float*)d_in[19];
  const float* ag    = (const float*)d_in[20];
  const float* abeta = (const float*)d_in[21];
  const float* amean = (const float*)d_in[22];
  const float* avar  = (const float*)d_in[23];
  const float* aw2   = (const float*)d_in[24];
  const float* ab2   = (const float*)d_in[25];
  const float* lw    = (const float*)d_in[26];
  const float* lb    = (const float*)d_in[27];

  char* ws = (char*)d_ws;
  size_t off = 0;
  auto alloc = [&](size_t bytes) -> void* {
    void* p = ws + off;
    off = (off + bytes + 255) & ~(size_t)255;
    return p;
  };

  bf16* ls_wb = (bf16*)alloc(32768 * 2);
  bf16* vwb   = (bf16*)alloc(65536 * 2);
  bf16* qwt   = (bf16*)alloc(65536 * 2);
  bf16* kwt   = (bf16*)alloc(65536 * 2);
  bf16* pw2b  = (bf16*)alloc(16384 * 2);
  bf16* pw2t  = (bf16*)alloc(16384 * 2);
  bf16* aw1b  = (bf16*)alloc(262144 * 2);
  bf16* aw2b  = (bf16*)alloc(262144 * 2);
  bf16* lwb   = (bf16*)alloc(32768 * 2);
  float* pe_scale = (float*)alloc(64 * 4);
  float* pe_shift = (float*)alloc(64 * 4);
  float* at_scale = (float*)alloc(1024 * 4);
  float* at_shift = (float*)alloc(1024 * 4);
  float* bq    = (float*)alloc(1024 * 4);
  float* bk    = (float*)alloc(1024 * 4);
  float* zeros = (float*)alloc(1024 * 4);
  int*  idx  = (int*)alloc((size_t)CC * 4);
  bf16* xT   = (bf16*)alloc((size_t)BN * CIN * 2);
  bf16* hT   = (bf16*)alloc((size_t)BN * DIM * 2);
  bf16* vTb  = (bf16*)alloc((size_t)BN * DIM * 2);
  bf16* Waq  = (bf16*)alloc((size_t)HIDN * DIM * 2);
  bf16* Wak  = (bf16*)alloc((size_t)HIDN * DIM * 2);
  bf16* Mwb  = (bf16*)alloc((size_t)HIDN * PH * 2);
  bf16* A1q  = (bf16*)alloc((size_t)BN * HIDN * 2);
  bf16* A1k  = (bf16*)alloc((size_t)BN * HIDN * 2);
  bf16* aggT = (bf16*)alloc((size_t)BN * DIM * 2);

  // 1. prep (823360 elems)
  prep_kernel<<<dim3((823360 + 255) / 256), 256, 0, stream>>>(
      ls_w, qw, kw, vw, pw2, aw1, aw2, lw, qb, kb, pb2,
      pb1, pg, pbeta, pmean, pvar, ab1, ag, abeta, amean, avar,
      ls_wb, vwb, qwt, kwt, pw2b, pw2t, aw1b, aw2b, lwb,
      pe_scale, pe_shift, at_scale, at_shift, bq, bk, zeros);

  // 2. transpose x -> xT
  transpose_x_kernel<<<dim3(BN * CIN / 256), 256, 0, stream>>>(x, xT);

  // 3. KNN
  knn_kernel<<<dim3(BN / 4), 256, 0, stream>>>(pos, idx);

  // 4. hT = ls_w . x + ls_b
  gemmT_kernel<128, true><<<dim3(BN / 64, DIM / 64), 256, 0, stream>>>(xT, ls_wb, ls_b, hT, DIM);

  // 5. weight-space GEMMs: Waq = aw1.qw, Wak = aw1.kw, Mw = aw1.pw2
  gemmT_kernel<256, true><<<dim3(HIDN / 64, DIM / 64), 256, 0, stream>>>(aw1b, qwt, zeros, Waq, DIM);
  gemmT_kernel<256, true><<<dim3(HIDN / 64, DIM / 64), 256, 0, stream>>>(aw1b, kwt, zeros, Wak, DIM);
  gemmT_kernel<256, true><<<dim3(HIDN / 64, PH / 64), 256, 0, stream>>>(aw1b, pw2t, zeros, Mwb, PH);

  // 6. v projection + A1q/A1k point-space GEMMs
  gemmT_kernel<256, true><<<dim3(BN / 64, DIM / 64), 256, 0, stream>>>(hT, vwb, vb, vTb, DIM);
  gemmT_kernel<256, true><<<dim3(BN / 64, HIDN / 64), 256, 0, stream>>>(hT, Waq, bq, A1q, HIDN);
  gemmT_kernel<256, true><<<dim3(BN / 64, HIDN / 64), 256, 0, stream>>>(hT, Wak, bk, A1k, HIDN);

  // 7. fused attention (decomposed)
  attn_fused_kernel<<<dim3(CC / 64), 256, 0, stream>>>(
      vTb, pos, idx, pw1, pe_scale, pe_shift, pw2b, pb2,
      Mwb, A1q, A1k, aw2b, at_scale, at_shift, ab2, aggT);

  // 8. y = lw . agg + lb + identity
  final_kernel<<<dim3(BN / 64, CIN / 64), 256, 0, stream>>>(aggT, lwb, lb, x, (float*)d_out);
}

// Round 5
// 533.687 us; speedup vs baseline: 1.2306x; 1.2306x over previous
//
#include <hip/hip_runtime.h>
#include <hip/hip_bf16.h>
#include <math.h>

#define B_    4
#define CIN   128
#define NPTS  2048
#define DIM   256
#define PH    64
#define HIDN  1024
#define KNN_  16
#define BN    (B_*NPTS)      /* 8192  */
#define CC    (BN*KNN_)      /* 131072 */
#define QKV   768
#define EPS_  1e-5f

typedef __bf16 bf16;
typedef __bf16 bf16x8 __attribute__((ext_vector_type(8)));
typedef __bf16 bf16x4 __attribute__((ext_vector_type(4)));
typedef float  f32x4  __attribute__((ext_vector_type(4)));

// ---------------------------------------------------------------------------
// prep: fp32->bf16 weight conversion + packed qkv weights + bn folding
// ---------------------------------------------------------------------------
__global__ __launch_bounds__(256) void prep_kernel(
    const float* __restrict__ ls_w, const float* __restrict__ qw,
    const float* __restrict__ kw,   const float* __restrict__ vw,
    const float* __restrict__ pw2,  const float* __restrict__ aw1,
    const float* __restrict__ aw2,  const float* __restrict__ lw,
    const float* __restrict__ qb,   const float* __restrict__ kb,
    const float* __restrict__ vb,
    const float* __restrict__ pb1,  const float* __restrict__ pg,
    const float* __restrict__ pbeta,const float* __restrict__ pmean,
    const float* __restrict__ pvar,
    const float* __restrict__ ab1,  const float* __restrict__ ag,
    const float* __restrict__ abeta,const float* __restrict__ amean,
    const float* __restrict__ avar,
    bf16* ls_wb, bf16* wqkvb, bf16* pw2b, bf16* aw1b, bf16* aw2b, bf16* lwb,
    float* pe_scale, float* pe_shift, float* at_scale, float* at_shift,
    float* bqkv)
{
  long e = (long)blockIdx.x * 256 + threadIdx.x;
  if (e < 32768)  { ls_wb[e] = (bf16)ls_w[e]; return; } e -= 32768;
  if (e < 196608) {                     // packed [qw; kw; vw] rows
    int row = (int)(e >> 8), col = (int)(e & 255);
    float v = (row < 256) ? qw[row * 256 + col]
            : (row < 512) ? kw[(row - 256) * 256 + col]
                          : vw[(row - 512) * 256 + col];
    wqkvb[e] = (bf16)v; return;
  } e -= 196608;
  if (e < 16384)  { pw2b[e] = (bf16)pw2[e];  return; } e -= 16384;
  if (e < 262144) { aw1b[e] = (bf16)aw1[e];  return; } e -= 262144;
  if (e < 262144) { aw2b[e] = (bf16)aw2[e];  return; } e -= 262144;
  if (e < 32768)  { lwb[e]  = (bf16)lw[e];   return; } e -= 32768;
  if (e < 64) {
    float sc = pg[e] * rsqrtf(pvar[e] + EPS_);
    pe_scale[e] = sc;
    pe_shift[e] = sc * pb1[e] + pbeta[e] - pmean[e] * sc;
    return;
  } e -= 64;
  if (e < 1024) {
    float sc = ag[e] * rsqrtf(avar[e] + EPS_);
    at_scale[e] = sc;
    at_shift[e] = sc * ab1[e] + abeta[e] - amean[e] * sc;
    return;
  } e -= 1024;
  if (e < 768) {
    bqkv[e] = (e < 256) ? qb[e] : (e < 512) ? kb[e - 256] : vb[e - 512];
  }
}

// ---------------------------------------------------------------------------
// transpose x (B,CIN,N) fp32 -> xT (BN, CIN) bf16  (channel-last)
// ---------------------------------------------------------------------------
__global__ __launch_bounds__(256) void transpose_x_kernel(
    const float* __restrict__ x, bf16* __restrict__ xT)
{
  long e = (long)blockIdx.x * 256 + threadIdx.x;
  int ch = (int)(e & (CIN - 1));
  long i = e >> 7;
  int n = (int)(i & (NPTS - 1));
  int b = (int)(i >> 11);
  xT[e] = (bf16)x[((long)b * CIN + ch) * NPTS + n];
}

// ---------------------------------------------------------------------------
// KNN: one WAVE per query point; dists in 32 regs/lane; shfl argmin x16
// ---------------------------------------------------------------------------
__global__ __launch_bounds__(256) void knn_kernel(
    const float* __restrict__ pos, int* __restrict__ idx_out)
{
  __shared__ float px[NPTS], py[NPTS], pz[NPTS];
  const int tid = threadIdx.x;
  const int lane = tid & 63, wave = tid >> 6;
  const int q = blockIdx.x * 4 + wave;
  const int b = q >> 11;
  const int n = q & (NPTS - 1);
  const float* p = pos + (long)b * 3 * NPTS;
  for (int j = tid; j < NPTS; j += 256) {
    px[j] = p[j]; py[j] = p[NPTS + j]; pz[j] = p[2 * NPTS + j];
  }
  __syncthreads();
  float qx = px[n], qy = py[n], qz = pz[n];
  float qs = qx * qx + qy * qy + qz * qz;
  float d[32];
#pragma unroll
  for (int j = 0; j < 32; ++j) {
    int pt = j * 64 + lane;
    float x = px[pt], y = py[pt], z = pz[pt];
    float s2 = x * x + y * y + z * z;
    float dt = qx * x + qy * y + qz * z;
    d[j] = qs + s2 - 2.f * dt;
  }
  for (int r = 0; r < KNN_; ++r) {
    float bv = 1e30f; int bj = 0;
#pragma unroll
    for (int j = 0; j < 32; ++j)
      if (d[j] < bv) { bv = d[j]; bj = j; }
    int bi = bj * 64 + lane;
#pragma unroll
    for (int off = 32; off >= 1; off >>= 1) {
      float ov = __shfl_xor(bv, off);
      int   oi = __shfl_xor(bi, off);
      if (ov < bv || (ov == bv && oi < bi)) { bv = ov; bi = oi; }
    }
    if (lane == 0) idx_out[(long)q * KNN_ + r] = bi;
#pragma unroll
    for (int j = 0; j < 32; ++j)
      if (bi == j * 64 + lane) d[j] = 1e30f;
  }
}

// ---------------------------------------------------------------------------
// generic channel-last GEMM: out[i][o] = sum_k inT[i][k]*W[o][k] + bias[o]
// ---------------------------------------------------------------------------
template<int KD, bool OBF16>
__global__ __launch_bounds__(256) void gemmT_kernel(
    const bf16* __restrict__ inT, const bf16* __restrict__ Wb,
    const float* __restrict__ bias, void* __restrict__ outp, int O)
{
  const int tid = threadIdx.x;
  const int lane = tid & 63, wave = tid >> 6;
  const int row16 = lane & 15, grp = lane >> 4;
  const long i0 = (long)blockIdx.x * 64 + (wave & 1) * 32;
  const long o0 = (long)blockIdx.y * 64 + (wave >> 1) * 32;
  f32x4 acc[2][2] = {};
  const bf16* a0p = inT + (i0 + row16) * KD + grp * 8;
  const bf16* a1p = a0p + 16 * KD;
  const bf16* b0p = Wb + (o0 + row16) * KD + grp * 8;
  const bf16* b1p = b0p + 16 * KD;
#pragma unroll
  for (int ks = 0; ks < KD / 32; ++ks) {
    bf16x8 a0 = *(const bf16x8*)(a0p + ks * 32);
    bf16x8 a1 = *(const bf16x8*)(a1p + ks * 32);
    bf16x8 b0 = *(const bf16x8*)(b0p + ks * 32);
    bf16x8 b1 = *(const bf16x8*)(b1p + ks * 32);
    acc[0][0] = __builtin_amdgcn_mfma_f32_16x16x32_bf16(a0, b0, acc[0][0], 0, 0, 0);
    acc[0][1] = __builtin_amdgcn_mfma_f32_16x16x32_bf16(a0, b1, acc[0][1], 0, 0, 0);
    acc[1][0] = __builtin_amdgcn_mfma_f32_16x16x32_bf16(a1, b0, acc[1][0], 0, 0, 0);
    acc[1][1] = __builtin_amdgcn_mfma_f32_16x16x32_bf16(a1, b1, acc[1][1], 0, 0, 0);
  }
#pragma unroll
  for (int ot = 0; ot < 2; ++ot) {
    long o = o0 + ot * 16 + row16;
    float bv = bias[o];
#pragma unroll
    for (int it = 0; it < 2; ++it) {
#pragma unroll
      for (int r = 0; r < 4; ++r) {
        long i = i0 + it * 16 + grp * 4 + r;
        float v = acc[it][ot][r] + bv;
        if (OBF16) ((bf16*)outp)[i * O + o] = (bf16)v;
        else       ((float*)outp)[i * O + o] = v;
      }
    }
  }
}

// ---------------------------------------------------------------------------
// FUSED attention v5 (round-3 structure, conflict-free u-build):
//   pe GEMM computed in BOTH operand orders:
//     accpeT (row=o,col=c): 4 consecutive o per lane -> vectorized u-build
//     accpe  (row=c,col=o): matches acc2 layout for softmax/agg
//   u-build: k gathered straight from global (bf16x4), q broadcast, single
//   ds_write_b64 per (ct,ot). No LDS staging pass, no scalar RMW.
// ---------------------------------------------------------------------------
__global__ __launch_bounds__(256, 3) void attn_fused_kernel(
    const bf16* __restrict__ qkvT, const float* __restrict__ pos,
    const int* __restrict__ idx, const float* __restrict__ pw1,
    const float* __restrict__ pe_scale, const float* __restrict__ pe_shift,
    const bf16* __restrict__ pw2b, const float* __restrict__ pb2,
    const bf16* __restrict__ aw1b, const bf16* __restrict__ aw2b,
    const float* __restrict__ at_scale, const float* __restrict__ at_shift,
    const float* __restrict__ ab2, bf16* __restrict__ aggT)
{
  __shared__ __align__(16) bf16 u_lds[64][264];   // 33.8 KB
  __shared__ __align__(16) bf16 tbuf[64 * 136];   // 17.4 KB (t / hid overlay)
  __shared__ float rel_lds[64][4];
  __shared__ int   idx_lds[64];
  bf16 (*t_lds)[136]  = (bf16(*)[136])tbuf;
  bf16 (*hid_lds)[72] = (bf16(*)[72])tbuf;

  const int tid = threadIdx.x;
  const int lane = tid & 63, wave = tid >> 6;
  const int row16 = lane & 15, grp = lane >> 4;
  const long c0 = (long)blockIdx.x * 64;
  const int bn0 = blockIdx.x * 4;
  const int b = bn0 >> 11;
  const float* pB = pos + (long)b * 3 * NPTS;
  const int os = wave * 64;             // output-channel slab
  const int hs = wave * 32;             // hidden slab within 128-chunk

  // ---- stage idx + pos_rel ----
  if (tid < 64) {
    int nb = idx[c0 + tid];
    idx_lds[tid] = nb;
    int n = (bn0 + (tid >> 4)) & (NPTS - 1);
    rel_lds[tid][0] = pB[n] - pB[nb];
    rel_lds[tid][1] = pB[NPTS + n] - pB[NPTS + nb];
    rel_lds[tid][2] = pB[2 * NPTS + n] - pB[2 * NPTS + nb];
  }
  __syncthreads();

  // ---- hid = relu(bn(pw1 . rel)) ----
  {
    int c = tid & 63, jq = tid >> 6;
    float rx = rel_lds[c][0], ry = rel_lds[c][1], rz = rel_lds[c][2];
#pragma unroll
    for (int jj = 0; jj < 16; ++jj) {
      int j = jq * 16 + jj;
      float v = pw1[j * 3] * rx + pw1[j * 3 + 1] * ry + pw1[j * 3 + 2] * rz;
      v = pe_scale[j] * v + pe_shift[j];
      hid_lds[c][j] = (bf16)fmaxf(v, 0.f);
    }
  }
  __syncthreads();

  // ---- pe GEMMs, both layouts ----
  f32x4 accpe[4][4] = {};    // row=c(grp*4+r), col=o(row16)  -> agg
  f32x4 accpeT[4][4] = {};   // row=o(grp*4+r), col=c(row16)  -> u-build
#pragma unroll
  for (int ks = 0; ks < 2; ++ks) {
    bf16x8 ah[4], bw[4];
#pragma unroll
    for (int ct = 0; ct < 4; ++ct)
      ah[ct] = *(const bf16x8*)&hid_lds[ct * 16 + row16][ks * 32 + grp * 8];
#pragma unroll
    for (int ot = 0; ot < 4; ++ot)
      bw[ot] = *(const bf16x8*)(pw2b + (long)(os + ot * 16 + row16) * PH + ks * 32 + grp * 8);
#pragma unroll
    for (int ct = 0; ct < 4; ++ct)
#pragma unroll
      for (int ot = 0; ot < 4; ++ot) {
        accpe[ct][ot]  = __builtin_amdgcn_mfma_f32_16x16x32_bf16(ah[ct], bw[ot], accpe[ct][ot], 0, 0, 0);
        accpeT[ct][ot] = __builtin_amdgcn_mfma_f32_16x16x32_bf16(bw[ot], ah[ct], accpeT[ct][ot], 0, 0, 0);
      }
  }

  // pe (bf16) in acc2 layout for the aggregation stage
  bf16x4 pe_bf[4][4];
#pragma unroll
  for (int ot = 0; ot < 4; ++ot) {
    float pb2v = pb2[os + ot * 16 + row16];
#pragma unroll
    for (int ct = 0; ct < 4; ++ct)
#pragma unroll
      for (int r = 0; r < 4; ++r)
        pe_bf[ct][ot][r] = (bf16)(accpe[ct][ot][r] + pb2v);
  }

  // ---- u-build: u[c][o4] = q - k_gather + peT, vector b64 stores ----
#pragma unroll
  for (int ct = 0; ct < 4; ++ct) {
    int nb = idx_lds[ct * 16 + row16];                 // c = ct*16+row16
    const bf16* krow = qkvT + ((long)b * NPTS + nb) * QKV + 256 + os;
    const bf16* qrow = qkvT + (long)(bn0 + ct) * QKV + os;
#pragma unroll
    for (int ot = 0; ot < 4; ++ot) {
      int o4 = ot * 16 + grp * 4;                      // offset within slab
      bf16x4 k4 = *(const bf16x4*)(krow + o4);
      bf16x4 q4 = *(const bf16x4*)(qrow + o4);
      f32x4 pb4 = *(const f32x4*)&pb2[os + o4];
      bf16x4 u4;
#pragma unroll
      for (int r = 0; r < 4; ++r)
        u4[r] = (bf16)((float)q4[r] - (float)k4[r] + accpeT[ct][ot][r] + pb4[r]);
      *(bf16x4*)&u_lds[ct * 16 + row16][os + o4] = u4;
    }
  }
  __syncthreads();

  // ---- MLP: attn = ab2 + aw2 . relu(bn(aw1 . u)), HID chunked at 128 ----
  f32x4 acc2[4][4] = {};
  for (int jc = 0; jc < 8; ++jc) {
    const int hg = jc * 128 + hs;
    f32x4 acc1[4][2] = {};
#pragma unroll
    for (int ks = 0; ks < 8; ++ks) {
      bf16x8 bu[4], aw[2];
#pragma unroll
      for (int ct = 0; ct < 4; ++ct)
        bu[ct] = *(const bf16x8*)&u_lds[ct * 16 + row16][ks * 32 + grp * 8];
#pragma unroll
      for (int jt = 0; jt < 2; ++jt)
        aw[jt] = *(const bf16x8*)(aw1b + (long)(hg + jt * 16 + row16) * DIM + ks * 32 + grp * 8);
#pragma unroll
      for (int ct = 0; ct < 4; ++ct)
#pragma unroll
        for (int jt = 0; jt < 2; ++jt)
          acc1[ct][jt] = __builtin_amdgcn_mfma_f32_16x16x32_bf16(aw[jt], bu[ct], acc1[ct][jt], 0, 0, 0);
    }
#pragma unroll
    for (int jt = 0; jt < 2; ++jt) {
      int jb = hg + jt * 16 + grp * 4;
      f32x4 sc4 = *(const f32x4*)&at_scale[jb];
      f32x4 sh4 = *(const f32x4*)&at_shift[jb];
#pragma unroll
      for (int ct = 0; ct < 4; ++ct) {
        bf16x4 pk;
#pragma unroll
        for (int r = 0; r < 4; ++r) {
          float v = sc4[r] * acc1[ct][jt][r] + sh4[r];
          pk[r] = (bf16)fmaxf(v, 0.f);
        }
        *(bf16x4*)&t_lds[ct * 16 + row16][hs + jt * 16 + grp * 4] = pk;
      }
    }
    __syncthreads();
#pragma unroll
    for (int ks2 = 0; ks2 < 4; ++ks2) {
      bf16x8 a2[4], b2;
#pragma unroll
      for (int ct = 0; ct < 4; ++ct)
        a2[ct] = *(const bf16x8*)&t_lds[ct * 16 + row16][ks2 * 32 + grp * 8];
#pragma unroll
      for (int ot = 0; ot < 4; ++ot) {
        b2 = *(const bf16x8*)(aw2b + (long)(os + ot * 16 + row16) * HIDN + jc * 128 + ks2 * 32 + grp * 8);
#pragma unroll
        for (int ct = 0; ct < 4; ++ct)
          acc2[ct][ot] = __builtin_amdgcn_mfma_f32_16x16x32_bf16(a2[ct], b2, acc2[ct][ot], 0, 0, 0);
      }
    }
    __syncthreads();
  }

  // ---- softmax over K + aggregation ----
#pragma unroll
  for (int ct = 0; ct < 4; ++ct) {
#pragma unroll
    for (int ot = 0; ot < 4; ++ot) {
      int o = os + ot * 16 + row16;
      float ab = ab2[o];
      float l[4];
      float m = -1e30f;
#pragma unroll
      for (int r = 0; r < 4; ++r) {
        l[r] = acc2[ct][ot][r] + ab;
        m = fmaxf(m, l[r]);
      }
      m = fmaxf(m, __shfl_xor(m, 16));
      m = fmaxf(m, __shfl_xor(m, 32));
      float s = 0.f;
#pragma unroll
      for (int r = 0; r < 4; ++r) { l[r] = expf(l[r] - m); s += l[r]; }
      s += __shfl_xor(s, 16);
      s += __shfl_xor(s, 32);
      float inv = 1.f / s;
      float agg = 0.f;
#pragma unroll
      for (int r = 0; r < 4; ++r) {
        int c = ct * 16 + grp * 4 + r;
        int nb = idx_lds[c];
        float vv = (float)qkvT[((long)b * NPTS + nb) * QKV + 512 + o];
        agg += l[r] * (vv + (float)pe_bf[ct][ot][r]);
      }
      agg *= inv;
      agg += __shfl_xor(agg, 16);
      agg += __shfl_xor(agg, 32);
      if (grp == 0) aggT[(long)(bn0 + ct) * DIM + o] = (bf16)agg;
    }
  }
}

// ---------------------------------------------------------------------------
// final: out[b][o][n] = lw . agg + lb + identity
// ---------------------------------------------------------------------------
__global__ __launch_bounds__(256) void final_kernel(
    const bf16* __restrict__ aggT, const bf16* __restrict__ lwb,
    const float* __restrict__ lb, const float* __restrict__ x,
    float* __restrict__ out)
{
  const int tid = threadIdx.x;
  const int lane = tid & 63, wave = tid >> 6;
  const int row16 = lane & 15, grp = lane >> 4;
  const long i0 = (long)blockIdx.x * 64 + (wave & 1) * 32;
  const int o0 = blockIdx.y * 64 + (wave >> 1) * 32;
  f32x4 acc[2][2] = {};
  const bf16* a0p = aggT + (i0 + row16) * DIM + grp * 8;
  const bf16* a1p = a0p + 16 * DIM;
  const bf16* b0p = lwb + (long)(o0 + row16) * DIM + grp * 8;
  const bf16* b1p = b0p + 16 * DIM;
#pragma unroll
  for (int ks = 0; ks < 8; ++ks) {
    bf16x8 a0 = *(const bf16x8*)(a0p + ks * 32);
    bf16x8 a1 = *(const bf16x8*)(a1p + ks * 32);
    bf16x8 b0 = *(const bf16x8*)(b0p + ks * 32);
    bf16x8 b1 = *(const bf16x8*)(b1p + ks * 32);
    acc[0][0] = __builtin_amdgcn_mfma_f32_16x16x32_bf16(a0, b0, acc[0][0], 0, 0, 0);
    acc[0][1] = __builtin_amdgcn_mfma_f32_16x16x32_bf16(a0, b1, acc[0][1], 0, 0, 0);
    acc[1][0] = __builtin_amdgcn_mfma_f32_16x16x32_bf16(a1, b0, acc[1][0], 0, 0, 0);
    acc[1][1] = __builtin_amdgcn_mfma_f32_16x16x32_bf16(a1, b1, acc[1][1], 0, 0, 0);
  }
#pragma unroll
  for (int ot = 0; ot < 2; ++ot) {
    int o = o0 + ot * 16 + row16;
    float bv = lb[o];
#pragma unroll
    for (int it = 0; it < 2; ++it) {
#pragma unroll
      for (int r = 0; r < 4; ++r) {
        long i = i0 + it * 16 + grp * 4 + r;
        int bb = (int)(i >> 11);
        int n = (int)(i & (NPTS - 1));
        long off = ((long)bb * CIN + o) * NPTS + n;
        out[off] = acc[it][ot][r] + bv + x[off];
      }
    }
  }
}

// ---------------------------------------------------------------------------
extern "C" void kernel_launch(void* const* d_in, const int* in_sizes, int n_in,
                              void* d_out, int out_size, void* d_ws, size_t ws_size,
                              hipStream_t stream)
{
  const float* x     = (const float*)d_in[0];
  const float* pos   = (const float*)d_in[1];
  const float* ls_w  = (const float*)d_in[2];
  const float* ls_b  = (const float*)d_in[3];
  const float* kw    = (const float*)d_in[4];
  const float* kb    = (const float*)d_in[5];
  const float* qw    = (const float*)d_in[6];
  const float* qb    = (const float*)d_in[7];
  const float* vw    = (const float*)d_in[8];
  const float* vb    = (const float*)d_in[9];
  const float* pw1   = (const float*)d_in[10];
  const float* pb1   = (const float*)d_in[11];
  const float* pg    = (const float*)d_in[12];
  const float* pbeta = (const float*)d_in[13];
  const float* pmean = (const float*)d_in[14];
  const float* pvar  = (const float*)d_in[15];
  const float* pw2   = (const float*)d_in[16];
  const float* pb2   = (const float*)d_in[17];
  const float* aw1   = (const float*)d_in[18];
  const float* ab1   = (const float*)d_in[19];
  const float* ag    = (const float*)d_in[20];
  const float* abeta = (const float*)d_in[21];
  const float* amean = (const float*)d_in[22];
  const float* avar  = (const float*)d_in[23];
  const float* aw2   = (const float*)d_in[24];
  const float* ab2   = (const float*)d_in[25];
  const float* lw    = (const float*)d_in[26];
  const float* lb    = (const float*)d_in[27];

  char* ws = (char*)d_ws;
  size_t off = 0;
  auto alloc = [&](size_t bytes) -> void* {
    void* p = ws + off;
    off = (off + bytes + 255) & ~(size_t)255;
    return p;
  };

  bf16* ls_wb = (bf16*)alloc(32768 * 2);
  bf16* wqkvb = (bf16*)alloc(196608 * 2);
  bf16* pw2b  = (bf16*)alloc(16384 * 2);
  bf16* aw1b  = (bf16*)alloc(262144 * 2);
  bf16* aw2b  = (bf16*)alloc(262144 * 2);
  bf16* lwb   = (bf16*)alloc(32768 * 2);
  float* pe_scale = (float*)alloc(64 * 4);
  float* pe_shift = (float*)alloc(64 * 4);
  float* at_scale = (float*)alloc(1024 * 4);
  float* at_shift = (float*)alloc(1024 * 4);
  float* bqkv = (float*)alloc(768 * 4);
  int*  idx  = (int*)alloc((size_t)CC * 4);
  bf16* xT   = (bf16*)alloc((size_t)BN * CIN * 2);
  bf16* hT   = (bf16*)alloc((size_t)BN * DIM * 2);
  bf16* qkvT = (bf16*)alloc((size_t)BN * QKV * 2);
  bf16* aggT = (bf16*)alloc((size_t)BN * DIM * 2);

  // 1. prep (804672 elems)
  prep_kernel<<<dim3((804672 + 255) / 256), 256, 0, stream>>>(
      ls_w, qw, kw, vw, pw2, aw1, aw2, lw, qb, kb, vb,
      pb1, pg, pbeta, pmean, pvar, ab1, ag, abeta, amean, avar,
      ls_wb, wqkvb, pw2b, aw1b, aw2b, lwb,
      pe_scale, pe_shift, at_scale, at_shift, bqkv);

  // 2. transpose x -> xT
  transpose_x_kernel<<<dim3(BN * CIN / 256), 256, 0, stream>>>(x, xT);

  // 3. KNN
  knn_kernel<<<dim3(BN / 4), 256, 0, stream>>>(pos, idx);

  // 4. hT = ls_w . x + ls_b
  gemmT_kernel<128, true><<<dim3(BN / 64, DIM / 64), 256, 0, stream>>>(xT, ls_wb, ls_b, hT, DIM);

  // 5. fused q|k|v projection (O=768)
  gemmT_kernel<256, true><<<dim3(BN / 64, QKV / 64), 256, 0, stream>>>(hT, wqkvb, bqkv, qkvT, QKV);

  // 6. fused attention (pe + u + MLP + softmax + agg)
  attn_fused_kernel<<<dim3(CC / 64), 256, 0, stream>>>(
      qkvT, pos, idx, pw1, pe_scale, pe_shift, pw2b, pb2,
      aw1b, aw2b, at_scale, at_shift, ab2, aggT);

  // 7. y = lw . agg + lb + identity
  final_kernel<<<dim3(BN / 64, CIN / 64), 256, 0, stream>>>(aggT, lwb, lb, x, (float*)d_out);
}